// Round 1
// baseline (572.205 us; speedup 1.0000x reference)
//
#include <hip/hip_runtime.h>

#define N_ROWS 65536
#define DIMS 256
#define NCLS 64

// ws float-index layout
#define SUM_S_OFF 0
#define SUM_T_OFF 16384
#define CNT_S_OFF 32768
#define CNT_T_OFF 32832
#define ACC_OFF   32896   // double (2 floats)
#define U_S_OFF   32900   // packed float4 [k0][c], k0=0..63, c=0..63
#define U_T_OFF   49284
#define U_ST_OFF  65668

__device__ __forceinline__ float wave_max(float v) {
#pragma unroll
  for (int m = 32; m > 0; m >>= 1) v = fmaxf(v, __shfl_xor(v, m, 64));
  return v;
}
__device__ __forceinline__ float wave_sum(float v) {
#pragma unroll
  for (int m = 32; m > 0; m >>= 1) v += __shfl_xor(v, m, 64);
  return v;
}

// ---------------------------------------------------------------------------
// Kernel 1: per-class segment sums + counts via LDS privatization.
// 256 blocks: [0,128) -> src, [128,256) -> trg. 512 rows/block, 256 threads
// (thread t owns dim t -> no races on lsum).
// ---------------------------------------------------------------------------
__global__ __launch_bounds__(256) void seg_sum_kernel(
    const float* __restrict__ src_feat, const float* __restrict__ trg_feat,
    const int* __restrict__ src_label, const int* __restrict__ trg_label,
    float* __restrict__ ws_f) {
  __shared__ float lsum[NCLS * DIMS];  // 64 KB
  const int tid = threadIdx.x;
  const bool is_trg = blockIdx.x >= 128;
  const int blk = is_trg ? (blockIdx.x - 128) : blockIdx.x;
  const float* feat = is_trg ? trg_feat : src_feat;
  const int* label = is_trg ? trg_label : src_label;
  float* gsum = ws_f + (is_trg ? SUM_T_OFF : SUM_S_OFF);
  float* gcnt = ws_f + (is_trg ? CNT_T_OFF : CNT_S_OFF);

  for (int i = tid; i < NCLS * DIMS; i += 256) lsum[i] = 0.f;
  __syncthreads();

  const int row0 = blk * 512;
  float cnt_local = 0.f;  // thread t (<64) counts occurrences of class t
  for (int r = 0; r < 512; r += 4) {
    int lb[4];
    float v[4];
#pragma unroll
    for (int i = 0; i < 4; ++i) {
      lb[i] = label[row0 + r + i];
      v[i] = feat[(size_t)(row0 + r + i) * DIMS + tid];
    }
#pragma unroll
    for (int i = 0; i < 4; ++i) {
      lsum[lb[i] * DIMS + tid] += v[i];
      if (tid < NCLS) cnt_local += (lb[i] == tid) ? 1.f : 0.f;
    }
  }
  __syncthreads();
  for (int c = 0; c < NCLS; ++c)
    atomicAdd(&gsum[c * DIMS + tid], lsum[c * DIMS + tid]);
  if (tid < NCLS) atomicAdd(&gcnt[tid], cnt_local);
}

// ---------------------------------------------------------------------------
// Kernel 2: class means, stored K-major packed as float4 per (k-chunk, class)
// so the main kernel's lane=class loads are coalesced dwordx4.
// ---------------------------------------------------------------------------
__global__ __launch_bounds__(64) void means_kernel(float* __restrict__ ws_f) {
  const int k0 = blockIdx.x;   // 0..63 (chunk of 4 dims)
  const int c = threadIdx.x;   // 0..63
  const float cs = ws_f[CNT_S_OFF + c];
  const float ct = ws_f[CNT_T_OFF + c];
  const float4 ss = *(const float4*)(ws_f + SUM_S_OFF + c * DIMS + k0 * 4);
  const float4 st = *(const float4*)(ws_f + SUM_T_OFF + c * DIMS + k0 * 4);
  float4* uS = (float4*)(ws_f + U_S_OFF);
  float4* uT = (float4*)(ws_f + U_T_OFF);
  float4* uST = (float4*)(ws_f + U_ST_OFF);
  const float cst = cs + ct;
  uS[k0 * 64 + c] = make_float4(ss.x / cs, ss.y / cs, ss.z / cs, ss.w / cs);
  uT[k0 * 64 + c] = make_float4(st.x / ct, st.y / ct, st.z / ct, st.w / ct);
  uST[k0 * 64 + c] = make_float4((ss.x + st.x) / cst, (ss.y + st.y) / cst,
                                 (ss.z + st.z) / cst, (ss.w + st.w) / cst);
}

// ---------------------------------------------------------------------------
// Kernel 3: fused 3x logits + softmax/KL + reduce.
// 4096 blocks x 256 threads; 32 rows/block, 8 rows/wave, lane = class.
// ---------------------------------------------------------------------------
__global__ __launch_bounds__(256) void main_kernel(
    const float* __restrict__ src_feat, const float* __restrict__ trg_feat,
    const float* __restrict__ ws_f, double* __restrict__ acc) {
  __shared__ float tile[32 * DIMS];  // 32 KB
  const int tid = threadIdx.x;
  const int row0 = blockIdx.x * 32;
  const float* base = (row0 < N_ROWS)
                          ? src_feat + (size_t)row0 * DIMS
                          : trg_feat + (size_t)(row0 - N_ROWS) * DIMS;
  const float4* g4 = (const float4*)base;
  float4* t4 = (float4*)tile;
#pragma unroll
  for (int i = 0; i < 8; ++i) t4[i * 256 + tid] = g4[i * 256 + tid];
  __syncthreads();

  const int wave = tid >> 6;
  const int lane = tid & 63;  // class index
  const float4* uS = (const float4*)(ws_f + U_S_OFF);
  const float4* uT = (const float4*)(ws_f + U_T_OFF);
  const float4* uST = (const float4*)(ws_f + U_ST_OFF);

  float aS[8], aT[8], aST[8];
#pragma unroll
  for (int j = 0; j < 8; ++j) { aS[j] = 0.f; aT[j] = 0.f; aST[j] = 0.f; }

  const float* wt = tile + wave * 8 * DIMS;
#pragma unroll 2
  for (int k0 = 0; k0 < 64; ++k0) {
    const float4 us = uS[k0 * 64 + lane];
    const float4 ut = uT[k0 * 64 + lane];
    const float4 ust = uST[k0 * 64 + lane];
#pragma unroll
    for (int j = 0; j < 8; ++j) {
      const float4 f = ((const float4*)(wt + j * DIMS))[k0];  // broadcast
      aS[j] = fmaf(f.w, us.w, fmaf(f.z, us.z, fmaf(f.y, us.y, fmaf(f.x, us.x, aS[j]))));
      aT[j] = fmaf(f.w, ut.w, fmaf(f.z, ut.z, fmaf(f.y, ut.y, fmaf(f.x, ut.x, aT[j]))));
      aST[j] = fmaf(f.w, ust.w, fmaf(f.z, ust.z, fmaf(f.y, ust.y, fmaf(f.x, ust.x, aST[j]))));
    }
  }

  // six KL sums grouped: pa(2la-lb-lc) + pb(2lb-la-lc) + pc(2lc-la-lb)
  float total = 0.f;
#pragma unroll
  for (int j = 0; j < 8; ++j) {
    const float a = aS[j], b = aT[j], c = aST[j];
    const float ma = wave_max(a);
    const float La = ma + __logf(wave_sum(__expf(a - ma)));
    const float mb = wave_max(b);
    const float Lb = mb + __logf(wave_sum(__expf(b - mb)));
    const float mc = wave_max(c);
    const float Lc = mc + __logf(wave_sum(__expf(c - mc)));
    const float la = a - La, lb = b - Lb, lc = c - Lc;
    const float pa = __expf(la), pb = __expf(lb), pc = __expf(lc);
    const float t = pa * ((la - lb) + (la - lc)) + pb * ((lb - la) + (lb - lc)) +
                    pc * ((lc - la) + (lc - lb));
    total += wave_sum(t);
  }
  if (lane == 0) atomicAdd(acc, (double)total);
}

// final = sum_of_6_kl_sums / (6 * 2N * C)
__global__ void finalize_kernel(const double* __restrict__ acc,
                                float* __restrict__ out) {
  out[0] = (float)(acc[0] / 50331648.0);  // 6 * 131072 * 64
}

extern "C" void kernel_launch(void* const* d_in, const int* in_sizes, int n_in,
                              void* d_out, int out_size, void* d_ws, size_t ws_size,
                              hipStream_t stream) {
  const float* src_feat = (const float*)d_in[0];
  const float* trg_feat = (const float*)d_in[1];
  const int* src_label = (const int*)d_in[2];
  const int* trg_label = (const int*)d_in[3];
  // d_in[4] (trg_feat_un) unused by the reference loss.
  float* ws_f = (float*)d_ws;
  double* acc = (double*)(ws_f + ACC_OFF);
  float* out = (float*)d_out;

  // zero sums, counts, accumulator (ws is poisoned 0xAA before every launch)
  hipMemsetAsync(d_ws, 0, (size_t)(ACC_OFF + 4) * sizeof(float), stream);

  seg_sum_kernel<<<256, 256, 0, stream>>>(src_feat, trg_feat, src_label,
                                          trg_label, ws_f);
  means_kernel<<<64, 64, 0, stream>>>(ws_f);
  main_kernel<<<4096, 256, 0, stream>>>(src_feat, trg_feat, ws_f, acc);
  finalize_kernel<<<1, 1, 0, stream>>>(acc, out);
}

// Round 2
// 315.342 us; speedup vs baseline: 1.8146x; 1.8146x over previous
//
#include <hip/hip_runtime.h>

#define N_ROWS 65536
#define DIMS 256
#define NCLS 64

// ---- ws float-index layout ----
#define P_SUM_S 0          // [8][64][256] partial sums, src
#define P_SUM_T 131072     // [8][64][256] partial sums, trg
#define P_CNT_S 262144     // [8][64]
#define P_CNT_T 262656     // [8][64]
#define F_SUM_S 263168     // [64][256]
#define F_SUM_T 279552     // [64][256]
#define ACC_OFF 296064     // double (2 floats), byte off 1184256 (8-aligned)
#define BPACK_OFF 296080   // bf16[12][8][64][8] = 24576 floats (16B aligned)

typedef __attribute__((ext_vector_type(8))) short bf16x8;
typedef __attribute__((ext_vector_type(4))) float f32x4;

__device__ __forceinline__ short f2bf(float f) {
  unsigned u = __float_as_uint(f);
  u += 0x7fffu + ((u >> 16) & 1u);  // round-to-nearest-even
  return (short)(u >> 16);
}

__device__ __forceinline__ float wave_sum64(float v) {
#pragma unroll
  for (int m = 32; m > 0; m >>= 1) v += __shfl_xor(v, m, 64);
  return v;
}
__device__ __forceinline__ float seg_max16(float v) {
#pragma unroll
  for (int m = 8; m > 0; m >>= 1) v = fmaxf(v, __shfl_xor(v, m, 64));
  return v;
}
__device__ __forceinline__ float seg_sum16(float v) {
#pragma unroll
  for (int m = 8; m > 0; m >>= 1) v += __shfl_xor(v, m, 64);
  return v;
}

// ---------------------------------------------------------------------------
// Kernel 1: per-class partial sums via LDS privatization.
// 512 blocks (256 src, 256 trg), 256 rows/block, 8 partial buffers (blk&7).
// ---------------------------------------------------------------------------
__global__ __launch_bounds__(256) void seg_sum_kernel(
    const float* __restrict__ src_feat, const float* __restrict__ trg_feat,
    const int* __restrict__ src_label, const int* __restrict__ trg_label,
    float* __restrict__ ws_f) {
  __shared__ float lsum[NCLS * DIMS];  // 64 KB
  const int tid = threadIdx.x;
  const bool is_trg = blockIdx.x >= 256;
  const int blk = is_trg ? (blockIdx.x - 256) : blockIdx.x;
  const int part = blockIdx.x & 7;
  const float* feat = is_trg ? trg_feat : src_feat;
  const int* label = is_trg ? trg_label : src_label;
  float* gsum = ws_f + (is_trg ? P_SUM_T : P_SUM_S) + part * 16384;
  float* gcnt = ws_f + (is_trg ? P_CNT_T : P_CNT_S) + part * 64;

  for (int i = tid; i < NCLS * DIMS; i += 256) lsum[i] = 0.f;
  __syncthreads();

  const int row0 = blk * 256;
  float cnt_local = 0.f;
  for (int r = 0; r < 256; r += 8) {
    int lb[8];
    float v[8];
#pragma unroll
    for (int i = 0; i < 8; ++i) {
      lb[i] = label[row0 + r + i];
      v[i] = feat[(size_t)(row0 + r + i) * DIMS + tid];
    }
#pragma unroll
    for (int i = 0; i < 8; ++i) {
      lsum[lb[i] * DIMS + tid] += v[i];
      if (tid < NCLS) cnt_local += (lb[i] == tid) ? 1.f : 0.f;
    }
  }
  __syncthreads();
  for (int c = 0; c < NCLS; ++c)
    atomicAdd(&gsum[c * DIMS + tid], lsum[c * DIMS + tid]);
  if (tid < NCLS) atomicAdd(&gcnt[tid], cnt_local);
}

// ---------------------------------------------------------------------------
// Kernel 2: reduce 8 partial sum buffers -> final sums. 128 blocks x 256.
// ---------------------------------------------------------------------------
__global__ __launch_bounds__(256) void reduce_kernel(float* __restrict__ ws_f) {
  const int i = blockIdx.x * 256 + threadIdx.x;  // 0..32767
  const int which = i >> 14;
  const int off = i & 16383;
  const float* pp = ws_f + (which ? P_SUM_T : P_SUM_S) + off;
  float s = 0.f;
#pragma unroll
  for (int p = 0; p < 8; ++p) s += pp[p * 16384];
  ws_f[(which ? F_SUM_T : F_SUM_S) + off] = s;
}

// ---------------------------------------------------------------------------
// Kernel 3: compute means and pack B fragments for mfma_f32_16x16x32_bf16.
// B frag: lane l holds u[class = tile*16 + (l&15)][k = s*32 + (l>>4)*8 + j].
// 12 blocks (mat*4+tile) x 64 threads.
// ---------------------------------------------------------------------------
__global__ __launch_bounds__(64) void pack_kernel(float* __restrict__ ws_f) {
  const int bx = blockIdx.x;  // mat*4 + tile
  const int mat = bx >> 2;
  const int tile = bx & 3;
  const int lane = threadIdx.x;
  const int c = tile * 16 + (lane & 15);

  float cs = 0.f, ct = 0.f;
#pragma unroll
  for (int p = 0; p < 8; ++p) {
    cs += ws_f[P_CNT_S + p * 64 + c];
    ct += ws_f[P_CNT_T + p * 64 + c];
  }

  bf16x8* out = (bf16x8*)(ws_f + BPACK_OFF);
  const float* ss_base = ws_f + F_SUM_S + c * DIMS;
  const float* st_base = ws_f + F_SUM_T + c * DIMS;

#pragma unroll
  for (int s = 0; s < 8; ++s) {
    const int k0 = s * 32 + (lane >> 4) * 8;
    bf16x8 v;
#pragma unroll
    for (int j = 0; j < 8; ++j) {
      const float ss = ss_base[k0 + j];
      const float st = st_base[k0 + j];
      float u;
      if (mat == 0) u = ss / cs;
      else if (mat == 1) u = st / ct;
      else u = (ss + st) / (cs + ct);
      v[j] = f2bf(u);
    }
    out[(bx * 8 + s) * 64 + lane] = v;
  }
}

// ---------------------------------------------------------------------------
// Kernel 4: MFMA logits (3 mats x 64 classes) + fused softmax/KL + reduce.
// 1024 blocks x 256 threads; 128 rows/block, 32 rows/wave (2 M-groups of 16).
// ---------------------------------------------------------------------------
__global__ __launch_bounds__(256, 2) void main_kernel(
    const float* __restrict__ src_feat, const float* __restrict__ trg_feat,
    const float* __restrict__ ws_f, double* __restrict__ acc_out) {
  const int tid = threadIdx.x;
  const int wave = tid >> 6;
  const int lane = tid & 63;
  const int row0 = blockIdx.x * 128 + wave * 32;  // global row of wave
  const float* base = (row0 < N_ROWS)
                          ? src_feat + (size_t)row0 * DIMS
                          : trg_feat + (size_t)(row0 - N_ROWS) * DIMS;
  // A frag addressing: row = g*16 + (lane&15), k = s*32 + (lane>>4)*8
  const float* ap = base + (size_t)((lane & 15) * DIMS + (lane >> 4) * 8);
  const bf16x8* bp = (const bf16x8*)(ws_f + BPACK_OFF);

  f32x4 C[3][4][2];
#pragma unroll
  for (int m = 0; m < 3; ++m)
#pragma unroll
    for (int t = 0; t < 4; ++t)
#pragma unroll
      for (int g = 0; g < 2; ++g) C[m][t][g] = (f32x4){0.f, 0.f, 0.f, 0.f};

#pragma unroll
  for (int s = 0; s < 8; ++s) {
    bf16x8 a[2];
#pragma unroll
    for (int g = 0; g < 2; ++g) {
      const float* p = ap + g * 16 * DIMS + s * 32;
      const float4 lo = *(const float4*)p;
      const float4 hi = *(const float4*)(p + 4);
      bf16x8 t;
      t[0] = f2bf(lo.x); t[1] = f2bf(lo.y); t[2] = f2bf(lo.z); t[3] = f2bf(lo.w);
      t[4] = f2bf(hi.x); t[5] = f2bf(hi.y); t[6] = f2bf(hi.z); t[7] = f2bf(hi.w);
      a[g] = t;
    }
#pragma unroll
    for (int mt = 0; mt < 12; ++mt) {
      const bf16x8 b = bp[(mt * 8 + s) * 64 + lane];
      C[mt >> 2][mt & 3][0] =
          __builtin_amdgcn_mfma_f32_16x16x32_bf16(a[0], b, C[mt >> 2][mt & 3][0], 0, 0, 0);
      C[mt >> 2][mt & 3][1] =
          __builtin_amdgcn_mfma_f32_16x16x32_bf16(a[1], b, C[mt >> 2][mt & 3][1], 0, 0, 0);
    }
  }

  // Epilogue: D lane mapping: row = g*16 + (lane>>4)*4 + r, class = t*16 + (lane&15).
  // Per-row reductions live in 16-lane segments (shfl_xor masks 1,2,4,8).
  float total = 0.f;
#pragma unroll
  for (int g = 0; g < 2; ++g) {
#pragma unroll
    for (int r = 0; r < 4; ++r) {
      float va[4], vb[4], vc[4];
#pragma unroll
      for (int t = 0; t < 4; ++t) {
        va[t] = C[0][t][g][r];
        vb[t] = C[1][t][g][r];
        vc[t] = C[2][t][g][r];
      }
      float ma = fmaxf(fmaxf(va[0], va[1]), fmaxf(va[2], va[3]));
      float mb = fmaxf(fmaxf(vb[0], vb[1]), fmaxf(vb[2], vb[3]));
      float mc = fmaxf(fmaxf(vc[0], vc[1]), fmaxf(vc[2], vc[3]));
      ma = seg_max16(ma); mb = seg_max16(mb); mc = seg_max16(mc);
      float ea[4], eb[4], ec[4];
      float sa = 0.f, sb = 0.f, sc = 0.f;
#pragma unroll
      for (int t = 0; t < 4; ++t) {
        ea[t] = __expf(va[t] - ma); sa += ea[t];
        eb[t] = __expf(vb[t] - mb); sb += eb[t];
        ec[t] = __expf(vc[t] - mc); sc += ec[t];
      }
      sa = seg_sum16(sa); sb = seg_sum16(sb); sc = seg_sum16(sc);
      const float La = ma + __logf(sa);
      const float Lb = mb + __logf(sb);
      const float Lc = mc + __logf(sc);
      const float isa = 1.f / sa, isb = 1.f / sb, isc = 1.f / sc;
#pragma unroll
      for (int t = 0; t < 4; ++t) {
        const float la = va[t] - La, lb = vb[t] - Lb, lc = vc[t] - Lc;
        const float pa = ea[t] * isa, pb = eb[t] * isb, pc = ec[t] * isc;
        total += pa * ((la - lb) + (la - lc)) + pb * ((lb - la) + (lb - lc)) +
                 pc * ((lc - la) + (lc - lb));
      }
    }
  }
  total = wave_sum64(total);
  if (lane == 0) atomicAdd(acc_out, (double)total);
}

// final = sum_of_6_kl_sums / (6 * 2N * C)
__global__ void finalize_kernel(const double* __restrict__ acc,
                                float* __restrict__ out) {
  out[0] = (float)(acc[0] / 50331648.0);  // 6 * 131072 * 64
}

extern "C" void kernel_launch(void* const* d_in, const int* in_sizes, int n_in,
                              void* d_out, int out_size, void* d_ws, size_t ws_size,
                              hipStream_t stream) {
  const float* src_feat = (const float*)d_in[0];
  const float* trg_feat = (const float*)d_in[1];
  const int* src_label = (const int*)d_in[2];
  const int* trg_label = (const int*)d_in[3];
  // d_in[4] (trg_feat_un) unused by the reference loss.
  float* ws_f = (float*)d_ws;
  double* acc = (double*)(ws_f + ACC_OFF);
  float* out = (float*)d_out;

  // zero the partial buffers and the accumulator
  hipMemsetAsync(d_ws, 0, (size_t)(P_CNT_T + 512) * sizeof(float), stream);
  hipMemsetAsync((void*)acc, 0, sizeof(double), stream);

  seg_sum_kernel<<<512, 256, 0, stream>>>(src_feat, trg_feat, src_label,
                                          trg_label, ws_f);
  reduce_kernel<<<128, 256, 0, stream>>>(ws_f);
  pack_kernel<<<12, 64, 0, stream>>>(ws_f);
  main_kernel<<<1024, 256, 0, stream>>>(src_feat, trg_feat, ws_f, acc);
  finalize_kernel<<<1, 1, 0, stream>>>(acc, out);
}